// Round 7
// baseline (429.337 us; speedup 1.0000x reference)
//
#include <hip/hip_runtime.h>
#include <cmath>

// x [B=4096][T=512][D=4], H=32, gates 4H=128 (PyTorch order i,f,g,o).
constexpr int T   = 512;
constexpr int D   = 4;
constexpr int H   = 32;
constexpr int BT  = 16;    // batch cols per block
constexpr int BLK = 128;   // 2 waves: wave0 = layer0, wave1 = layer1
constexpr int LAG = 8;     // L2 time lag == barrier interval
constexpr int NS  = 16;    // h0 ring slots (= 2*LAG)

constexpr float LOG2E     = 1.44269504088896340736f;
constexpr float NEG2LOG2E = -2.88539008177792681472f;

// x staged as FULL zero-padded B-fragments (8 shorts/t). Col stride 4104
// shorts = 2052 dwords ≡ 4 (mod 32): broadcast b128 reads land 2-way per
// bank-quad (free). 16*4104*2B = 131.3 KB. (Proven R15-R17.)
constexpr int XSTRIDE = 4104;
// h row stride 40 shorts = 20 dwords: b128 frag reads have bank-quad index
// (5*nl+q) mod 8 — exactly 2-way (nl vs nl+8) = free (proven R15-R17).
constexpr int HSTR = 40;

typedef short bf8 __attribute__((ext_vector_type(8)));  // 8 bf16 (4 VGPRs)
typedef float f4  __attribute__((ext_vector_type(4)));  // MFMA C/D
typedef float f2  __attribute__((ext_vector_type(2)));  // packed-f32 pair

// fp32 -> bf16 round-to-nearest-even
static __device__ __forceinline__ short bf16_rtn(float v) {
    unsigned u = __float_as_uint(v);
    u += 0x7FFFu + ((u >> 16) & 1u);
    return (short)(u >> 16);
}

// R19 (resubmit — R6 bench was a broker timeout, no data):
// R18's wave-local ring structure with the two UNPROVEN components removed
// (accuracy bisect — R18 failed absmax 8.5e-4 vs 5.8e-4 threshold):
//  - x restored to the R15-proven LDS staging (bf16_rtn, XSTRIDE layout);
//    the cvt_pk-for-x path and the 8-deep register FIFO are gone.
//  - cvt_pk kept ONLY for h (proven passing in R16/R17).
//  - ring/parity logic unchanged (re-verified by concrete slot trace).
// Structure: wave0 owns ALL of layer0 (8 gate tiles x 2-chain = 16 MFMA/step,
// act on 8 units/lane); wave1 = layer1 lagging LAG=8 steps via 16-slot ring;
// __syncthreads only once per 8 steps.
__global__ __launch_bounds__(BLK, 1) void lstm_wl(
    const float* __restrict__ x,
    const float* __restrict__ W_ih0, const float* __restrict__ W_hh0,
    const float* __restrict__ b_ih0, const float* __restrict__ b_hh0,
    const float* __restrict__ W_ih1, const float* __restrict__ W_hh1,
    const float* __restrict__ b_ih1, const float* __restrict__ b_hh1,
    const float* __restrict__ W_out, const float* __restrict__ b_out,
    float* __restrict__ out)
{
    __shared__ __align__(16) short xbf[16 * XSTRIDE];   // 131.3 KB staged x frags
    __shared__ __align__(16) short h0r[NS][16][HSTR];   // 20.5 KB h0 ring
    __shared__ __align__(16) short h1d[2][16][HSTR];    // L2 own-recurrence dbuf
    __shared__ __align__(16) float h1f[16][36];         // final h1 fp32 for head

    const int tid  = threadIdx.x;
    const int isL0 = (tid < 64);       // wave 0 = layer 0
    const int lane = tid & 63;
    const int q    = lane >> 4;        // quad
    const int nl   = lane & 15;        // batch col
    const int b0   = blockIdx.x * BT;

    // ---- stage x -> zero-padded bf16 fragments (R15-proven path) ----
    // col-minor indexing: conflict-free LDS writes, 64B-coalesced global reads.
    for (int idx = tid; idx < 16 * T; idx += BLK) {
        const int col = idx & 15;
        const int t   = idx >> 4;
        float4 xv = *(const float4*)(x + ((size_t)(b0 + col) * T + t) * D);
        bf8 v = {0, 0, 0, 0, 0, 0, 0, 0};
        v[0] = bf16_rtn(xv.x); v[1] = bf16_rtn(xv.y);
        v[2] = bf16_rtn(xv.z); v[3] = bf16_rtn(xv.w);
        *(bf8*)&xbf[col * XSTRIDE + t * 8] = v;
    }
    // zero ring (h0(-1)=0 via slot 15) + h1 dbuf (h1(-1)=0)
    for (int idx = tid; idx < NS * 16 * HSTR; idx += BLK) (&h0r[0][0][0])[idx] = 0;
    for (int idx = tid; idx < 2 * 16 * HSTR; idx += BLK) (&h1d[0][0][0])[idx] = 0;

    // ---- weights: tile (g, hf) rows = 32g + 16hf + nl, k = 8q+j.
    // w1 dotted with the cross-layer-fresh operand (L0: W_hh0 vs h0(t-1);
    // L2: W_ih1 vs h0(t-LAG)); w2 with the other (L0: W_ih0 vs x, K-padded;
    // L2: W_hh1 vs h1(t-1)). Rows pre-scaled for exp2-domain act.
    const float* W1 = isL0 ? W_hh0 : W_ih1;
    bf8 w1[4][2], w2[4][2];
    f4  bias[4][2];
    #pragma unroll
    for (int g = 0; g < 4; ++g) {
        const float sc = (g == 2) ? NEG2LOG2E : -LOG2E;
        #pragma unroll
        for (int hf = 0; hf < 2; ++hf) {
            const int row = 32 * g + 16 * hf + nl;
            #pragma unroll
            for (int j = 0; j < 8; ++j) {
                w1[g][hf][j] = bf16_rtn(W1[row * H + 8 * q + j] * sc);
                float v2 = isL0 ? ((q == 0 && j < 4) ? W_ih0[row * D + j] : 0.0f)
                                : W_hh1[row * H + 8 * q + j];
                w2[g][hf][j] = bf16_rtn(v2 * sc);
            }
            #pragma unroll
            for (int r = 0; r < 4; ++r) {
                const int gr = 32 * g + 16 * hf + 4 * q + r;
                bias[g][hf][r] = sc * (isL0 ? (b_ih0[gr] + b_hh0[gr])
                                            : (b_ih1[gr] + b_hh1[gr]));
            }
        }
    }

    // cell state: cs[half][pair], 8 fp32 per lane (units 16hf + 4q + 2p + {0,1})
    f2 cs[2][2];
    cs[0][0] = 0.0f; cs[0][1] = 0.0f; cs[1][0] = 0.0f; cs[1][1] = 0.0f;

    const short* xcol = &xbf[nl * XSTRIDE];

    __syncthreads();

    // ---- packed activation for one unit-pair (identical math to R16/17) ----
    auto actpair = [&](f2& c2, float zi0, float zi1, float zf0, float zf1,
                       float zg0, float zg1, float zo0, float zo1,
                       unsigned& pkd, f2& hv) {
        f2 ei, ef, eg, eo, ec;
        ei.x = __builtin_amdgcn_exp2f(zi0); ei.y = __builtin_amdgcn_exp2f(zi1);
        ef.x = __builtin_amdgcn_exp2f(zf0); ef.y = __builtin_amdgcn_exp2f(zf1);
        eg.x = __builtin_amdgcn_exp2f(zg0); eg.y = __builtin_amdgcn_exp2f(zg1);
        eo.x = __builtin_amdgcn_exp2f(zo0); eo.y = __builtin_amdgcn_exp2f(zo1);
        f2 D1 = 1.0f + ef;
        f2 D2 = (1.0f + ei) * (1.0f + eg);
        f2 Dm = D1 * D2;
        float R = __builtin_amdgcn_rcpf(Dm.x * Dm.y);
        f2 rD; rD.x = R * Dm.y; rD.y = R * Dm.x;
        c2 = (c2 * D2 + (1.0f - eg) * D1) * rD;
        ec.x = __builtin_amdgcn_exp2f(c2.x * NEG2LOG2E);
        ec.y = __builtin_amdgcn_exp2f(c2.y * NEG2LOG2E);
        f2 Do = (1.0f + eo) * (1.0f + ec);
        float Ro = __builtin_amdgcn_rcpf(Do.x * Do.y);
        f2 ro; ro.x = Ro * Do.y; ro.y = Ro * Do.x;
        hv = (1.0f - ec) * ro;
        asm("v_cvt_pk_bf16_f32 %0, %1, %2" : "=v"(pkd) : "v"(hv.x), "v"(hv.y));
    };

    // ---- one 8-step group; barrier at the end. t0 multiple of 8;
    // sbase = (t0/8 & 1)*8 so slot = t mod 16 with compile-time u offset.
    auto group8 = [&](const int t0, const int sbase, const bool do0, const bool do1) {
        #pragma unroll
        for (int u = 0; u < 8; ++u) {
            if (do0 && isL0) {
                // x(t) fragment from staged LDS (pre-padded, bf16_rtn)
                bf8 b2 = *(const bf8*)&xcol[(t0 + u) * 8];
                // h0(t-1) frag: own write from previous step (same-wave DS, in-order)
                const int sr = (sbase + u - 1) & (NS - 1);
                bf8 b1 = *(const bf8*)&h0r[sr][nl][8 * q];
                f4 acc[4][2];
                #pragma unroll
                for (int g = 0; g < 4; ++g)
                    #pragma unroll
                    for (int hf = 0; hf < 2; ++hf) {
                        f4 A = __builtin_amdgcn_mfma_f32_16x16x32_bf16(w2[g][hf], b2, bias[g][hf], 0, 0, 0);
                        acc[g][hf] = __builtin_amdgcn_mfma_f32_16x16x32_bf16(w1[g][hf], b1, A, 0, 0, 0);
                    }
                unsigned pka, pkb; f2 hv;
                const int sw = sbase + u;
                actpair(cs[0][0], acc[0][0][0], acc[0][0][1], acc[1][0][0], acc[1][0][1],
                        acc[2][0][0], acc[2][0][1], acc[3][0][0], acc[3][0][1], pka, hv);
                actpair(cs[0][1], acc[0][0][2], acc[0][0][3], acc[1][0][2], acc[1][0][3],
                        acc[2][0][2], acc[2][0][3], acc[3][0][2], acc[3][0][3], pkb, hv);
                int2 wlo; wlo.x = (int)pka; wlo.y = (int)pkb;
                *(int2*)&h0r[sw][nl][4 * q] = wlo;           // units 4q..4q+3
                actpair(cs[1][0], acc[0][1][0], acc[0][1][1], acc[1][1][0], acc[1][1][1],
                        acc[2][1][0], acc[2][1][1], acc[3][1][0], acc[3][1][1], pka, hv);
                actpair(cs[1][1], acc[0][1][2], acc[0][1][3], acc[1][1][2], acc[1][1][3],
                        acc[2][1][2], acc[2][1][3], acc[3][1][2], acc[3][1][3], pkb, hv);
                int2 whi; whi.x = (int)pka; whi.y = (int)pkb;
                *(int2*)&h0r[sw][nl][16 + 4 * q] = whi;      // units 16+4q..+3
            }
            if (do1 && !isL0) {
                const int jj = t0 + u - LAG;        // layer-2 time
                const int wb = u & 1;               // t0,LAG even -> jj&1 == u&1
                const int rb = wb ^ 1;
                const int sb = (sbase + u + 8) & (NS - 1);   // h0(jj) slot
                bf8 b1 = *(const bf8*)&h0r[sb][nl][8 * q];   // h0(jj), W_ih1 side
                bf8 b2 = *(const bf8*)&h1d[rb][nl][8 * q];   // h1(jj-1), W_hh1 side
                f4 acc[4][2];
                #pragma unroll
                for (int g = 0; g < 4; ++g)
                    #pragma unroll
                    for (int hf = 0; hf < 2; ++hf) {
                        f4 A = __builtin_amdgcn_mfma_f32_16x16x32_bf16(w2[g][hf], b2, bias[g][hf], 0, 0, 0);
                        acc[g][hf] = __builtin_amdgcn_mfma_f32_16x16x32_bf16(w1[g][hf], b1, A, 0, 0, 0);
                    }
                unsigned pka, pkb; f2 hv0, hv1, hv2, hv3;
                actpair(cs[0][0], acc[0][0][0], acc[0][0][1], acc[1][0][0], acc[1][0][1],
                        acc[2][0][0], acc[2][0][1], acc[3][0][0], acc[3][0][1], pka, hv0);
                actpair(cs[0][1], acc[0][0][2], acc[0][0][3], acc[1][0][2], acc[1][0][3],
                        acc[2][0][2], acc[2][0][3], acc[3][0][2], acc[3][0][3], pkb, hv1);
                int2 wlo; wlo.x = (int)pka; wlo.y = (int)pkb;
                *(int2*)&h1d[wb][nl][4 * q] = wlo;
                actpair(cs[1][0], acc[0][1][0], acc[0][1][1], acc[1][1][0], acc[1][1][1],
                        acc[2][1][0], acc[2][1][1], acc[3][1][0], acc[3][1][1], pka, hv2);
                actpair(cs[1][1], acc[0][1][2], acc[0][1][3], acc[1][1][2], acc[1][1][3],
                        acc[2][1][2], acc[2][1][3], acc[3][1][2], acc[3][1][3], pkb, hv3);
                int2 whi; whi.x = (int)pka; whi.y = (int)pkb;
                *(int2*)&h1d[wb][nl][16 + 4 * q] = whi;
                if (jj == T - 1) {   // h1(T-1) fp32 for the output head
                    float2 a; a.x = hv0.x; a.y = hv0.y;
                    float2 b; b.x = hv1.x; b.y = hv1.y;
                    float2 c; c.x = hv2.x; c.y = hv2.y;
                    float2 d; d.x = hv3.x; d.y = hv3.y;
                    *(float2*)&h1f[nl][4 * q]          = a;
                    *(float2*)&h1f[nl][4 * q + 2]      = b;
                    *(float2*)&h1f[nl][16 + 4 * q]     = c;
                    *(float2*)&h1f[nl][16 + 4 * q + 2] = d;
                }
            }
        }
        __syncthreads();   // h0(t0..t0+7) now visible to L2's reads next group
    };

    group8(0, 0, true, false);                 // t=0..7: L0 only
    #pragma unroll 1
    for (int g = 1; g < 64; ++g)
        group8(8 * g, (g & 1) * 8, true, true);
    group8(T, 0, false, true);                 // flush: L2 jj=504..511 (g=64 even -> sbase=0)

    // ---- output head: out[b0+n] = b_out + W_out . h1(T-1) ----
    if (tid < BT) {
        float acc = b_out[0];
        #pragma unroll
        for (int u = 0; u < H; ++u) acc = fmaf(W_out[u], h1f[tid][u], acc);
        out[b0 + tid] = acc;
    }
}

extern "C" void kernel_launch(void* const* d_in, const int* in_sizes, int n_in,
                              void* d_out, int out_size, void* d_ws, size_t ws_size,
                              hipStream_t stream) {
    const float* x     = (const float*)d_in[0];
    const float* W_ih0 = (const float*)d_in[1];
    const float* W_hh0 = (const float*)d_in[2];
    const float* b_ih0 = (const float*)d_in[3];
    const float* b_hh0 = (const float*)d_in[4];
    const float* W_ih1 = (const float*)d_in[5];
    const float* W_hh1 = (const float*)d_in[6];
    const float* b_ih1 = (const float*)d_in[7];
    const float* b_hh1 = (const float*)d_in[8];
    const float* W_out = (const float*)d_in[9];
    const float* b_out = (const float*)d_in[10];
    float* out = (float*)d_out;

    const int B = out_size;          // 4096
    lstm_wl<<<B / BT, BLK, 0, stream>>>(x, W_ih0, W_hh0, b_ih0, b_hh0,
                                        W_ih1, W_hh1, b_ih1, b_hh1,
                                        W_out, b_out, out);
}

// Round 8
// 309.381 us; speedup vs baseline: 1.3877x; 1.3877x over previous
//
#include <hip/hip_runtime.h>
#include <cmath>

// x [B=4096][T=512][D=4], H=32, gates 4H=128 (PyTorch order i,f,g,o).
constexpr int T   = 512;
constexpr int D   = 4;
constexpr int H   = 32;
constexpr int BT  = 16;    // batch cols per block — ALL real
constexpr int BLK = 256;   // 4 waves: (layer, unit-half)

constexpr float LOG2E     = 1.44269504088896340736f;
constexpr float NEG2LOG2E = -2.88539008177792681472f;

// x staged as FULL zero-padded B-fragments (8 shorts/t). Col stride 4104
// shorts = 2052 dwords ≡ 4 (mod 32): the 16 per-iter broadcast b128 reads
// land 2-way per bank-quad (free). 16*4104*2B = 131.3 KB.
constexpr int XSTRIDE = 4104;
// h row stride 40 shorts = 20 dwords: b128 frag reads have bank-quad index
// (5*nl+q) mod 8 — exactly 2-way (nl vs nl+8) = free.
constexpr int HSTR = 40;

typedef short bf8 __attribute__((ext_vector_type(8)));  // 8 bf16 (4 VGPRs)
typedef float f4  __attribute__((ext_vector_type(4)));  // MFMA C/D
typedef float f2  __attribute__((ext_vector_type(2)));  // packed-f32 pair

// fp32 -> bf16 round-to-nearest-even (staging path)
static __device__ __forceinline__ short bf16_rtn(float v) {
    unsigned u = __float_as_uint(v);
    u += 0x7FFFu + ((u >> 16) & 1u);
    return (short)(u >> 16);
}

// R20 = R16 (best passing: 221 µs dispatch) + two chain cuts:
//  1. x-frag PRELOAD across the barrier: xbf is read-only, so step i+1's
//     L1 B-operand is ds_read BEFORE step i's __syncthreads. Post-barrier
//     the L1 chain starts with only the h0 read outstanding.
//  2. Independent MFMAs + f4 add (w2·b2+bias) + (w1·b1+0): removes the
//     MFMA->MFMA serial dependency (~25-30 cy) at +2 pk_add/gate.
// Everything else byte-identical to R16 (R17/R19 structural detours
// measured flat/worse; R16's topology is the unique full-distribution one).
__global__ __launch_bounds__(BLK, 1) void lstm_bf16p(
    const float* __restrict__ x,
    const float* __restrict__ W_ih0, const float* __restrict__ W_hh0,
    const float* __restrict__ b_ih0, const float* __restrict__ b_hh0,
    const float* __restrict__ W_ih1, const float* __restrict__ W_hh1,
    const float* __restrict__ b_ih1, const float* __restrict__ b_hh1,
    const float* __restrict__ W_out, const float* __restrict__ b_out,
    float* __restrict__ out)
{
    __shared__ __align__(16) short xbf[16 * XSTRIDE];   // 131.3 KB staged x frags
    __shared__ __align__(16) short h0b[2][16][HSTR];    // h, [buf][col][unit]
    __shared__ __align__(16) short h1b[2][16][HSTR];
    __shared__ __align__(16) float h1f[16][36];         // final h1 fp32 for the head

    const int tid   = threadIdx.x;
    const int w     = tid >> 6;
    const int lane  = tid & 63;
    const int q     = lane >> 4;       // quad
    const int nl    = lane & 15;       // batch col (all real)
    const int layer = w >> 1;          // 0: L1, 1: L2
    const int ug    = (w & 1) << 4;    // unit group offset 0 / 16
    const int b0    = blockIdx.x * BT;

    // ---- stage x -> zero-padded bf16 fragments ----
    for (int idx = tid; idx < 16 * T; idx += BLK) {
        const int col = idx & 15;
        const int t   = idx >> 4;
        float4 xv = *(const float4*)(x + ((size_t)(b0 + col) * T + t) * D);
        bf8 v = {0, 0, 0, 0, 0, 0, 0, 0};
        v[0] = bf16_rtn(xv.x); v[1] = bf16_rtn(xv.y);
        v[2] = bf16_rtn(xv.z); v[3] = bf16_rtn(xv.w);
        *(bf8*)&xbf[col * XSTRIDE + t * 8] = v;
    }
    // zero both h buffers
    for (int idx = tid; idx < 2 * 16 * HSTR; idx += BLK) {
        (&h0b[0][0][0])[idx] = 0;
        (&h1b[0][0][0])[idx] = 0;
    }

    // ---- weights: tile g = gate type. A-frag row = 32g + ug + nl, k = 8q+j.
    const float* W1 = layer ? W_ih1 : W_hh0;
    bf8 w1[4], w2[4];
    f4  bias[4];
    #pragma unroll
    for (int g = 0; g < 4; ++g) {
        const float sc = (g == 2) ? NEG2LOG2E : -LOG2E;
        const int row = 32 * g + ug + nl;
        #pragma unroll
        for (int j = 0; j < 8; ++j) {
            w1[g][j] = bf16_rtn(W1[row * H + 8 * q + j] * sc);
            float v2 = layer ? W_hh1[row * H + 8 * q + j]
                             : ((q == 0 && j < 4) ? W_ih0[row * D + j] : 0.0f);
            w2[g][j] = bf16_rtn(v2 * sc);
        }
        #pragma unroll
        for (int r = 0; r < 4; ++r) {
            const int gr = 32 * g + ug + 4 * q + r;
            bias[g][r] = sc * (layer ? (b_ih1[gr] + b_hh1[gr])
                                     : (b_ih0[gr] + b_hh0[gr]));
        }
    }

    // cell state, fp32, lane-local — two packed pairs (r01, r23)
    f2 cA; cA.x = 0.0f; cA.y = 0.0f;
    f2 cB; cB.x = 0.0f; cB.y = 0.0f;

    const short* xcol = &xbf[nl * XSTRIDE];

    __syncthreads();

    // preloaded x fragment for the NEXT step (L1 path); read pre-barrier
    bf8 b2x = *(const bf8*)&xcol[0];

    // ---- packed activation for one r-pair ----
    // acc components pre-scaled: -log2e*z (i,f,o) / -2log2e*z (g).
    // c' = c/(1+ef) + (1-eg)/((1+ei)(1+eg));  h = (1-ec)/((1+eo)(1+ec)).
    // One rcp per pair per site via R=rcp(a*b) -> 1/a = R*b, 1/b = R*a.
    auto actpair = [&](f2& c2, float zi0, float zi1, float zf0, float zf1,
                       float zg0, float zg1, float zo0, float zo1,
                       unsigned& pkd, f2& hv) {
        f2 ei, ef, eg, eo, ec;
        ei.x = __builtin_amdgcn_exp2f(zi0); ei.y = __builtin_amdgcn_exp2f(zi1);
        ef.x = __builtin_amdgcn_exp2f(zf0); ef.y = __builtin_amdgcn_exp2f(zf1);
        eg.x = __builtin_amdgcn_exp2f(zg0); eg.y = __builtin_amdgcn_exp2f(zg1);
        eo.x = __builtin_amdgcn_exp2f(zo0); eo.y = __builtin_amdgcn_exp2f(zo1);
        f2 D1 = 1.0f + ef;
        f2 D2 = (1.0f + ei) * (1.0f + eg);
        f2 Dm = D1 * D2;
        float R = __builtin_amdgcn_rcpf(Dm.x * Dm.y);
        f2 rD; rD.x = R * Dm.y; rD.y = R * Dm.x;
        c2 = (c2 * D2 + (1.0f - eg) * D1) * rD;
        ec.x = __builtin_amdgcn_exp2f(c2.x * NEG2LOG2E);
        ec.y = __builtin_amdgcn_exp2f(c2.y * NEG2LOG2E);
        f2 Do = (1.0f + eo) * (1.0f + ec);
        float Ro = __builtin_amdgcn_rcpf(Do.x * Do.y);
        f2 ro; ro.x = Ro * Do.y; ro.y = Ro * Do.x;
        hv = (1.0f - ec) * ro;
        // dword = [bf16(hv.y) | bf16(hv.x)] — RNE pack, 1 instr
        asm("v_cvt_pk_bf16_f32 %0, %1, %2" : "=v"(pkd) : "v"(hv.x), "v"(hv.y));
    };

    // ---- one timestep; rb/wb are compile-time literals at each call site ----
    auto body = [&](const int i, const int rb, const int wb) {
        bf8 b2;
        if (layer == 0) {   // x(i) fragment — PRELOADED before the last barrier
            b2 = b2x;
        } else {            // h1(i-2)
            b2 = *(const bf8*)&h1b[rb][nl][8 * q];
        }
        bf8 b1 = *(const bf8*)&h0b[rb][nl][8 * q];              // h0(i-1)

        // ---- 8 MFMAs: 4 gate tiles x 2 INDEPENDENT + f4 add ----
        const f4 zf4 = {0.0f, 0.0f, 0.0f, 0.0f};
        f4 acc[4];
        #pragma unroll
        for (int g = 0; g < 4; ++g) {
            f4 A1 = __builtin_amdgcn_mfma_f32_16x16x32_bf16(w2[g], b2, bias[g], 0, 0, 0);
            f4 A2 = __builtin_amdgcn_mfma_f32_16x16x32_bf16(w1[g], b1, zf4,     0, 0, 0);
            acc[g] = A1 + A2;
        }

        // ---- lane-local state update: units ug+4q+r, col nl ----
        const bool act = layer ? (i >= 1) : (i < T);
        if (act) {
            unsigned pk0, pk1;
            f2 hvA, hvB;
            actpair(cA, acc[0][0], acc[0][1], acc[1][0], acc[1][1],
                        acc[2][0], acc[2][1], acc[3][0], acc[3][1], pk0, hvA);
            actpair(cB, acc[0][2], acc[0][3], acc[1][2], acc[1][3],
                        acc[2][2], acc[2][3], acc[3][2], acc[3][3], pk1, hvB);
            int2 hh; hh.x = (int)pk0; hh.y = (int)pk1;
            if (layer == 0) {
                *(int2*)&h0b[wb][nl][ug + 4 * q] = hh;
            } else {
                *(int2*)&h1b[wb][nl][ug + 4 * q] = hh;
                if (i == T) {   // h1(T-1), fp32, for the output head
                    float4 hw;
                    hw.x = hvA.x; hw.y = hvA.y; hw.z = hvB.x; hw.w = hvB.y;
                    *(float4*)&h1f[nl][ug + 4 * q] = hw;
                }
            }
        }
        // preload NEXT step's x fragment BEFORE the barrier (xbf read-only;
        // completion folds into this barrier's drain, off next step's chain)
        b2x = *(const bf8*)&xcol[((i + 1) & (T - 1)) * 8];
        __syncthreads();   // buffer wb becomes rb of the next step
    };

    #pragma unroll 1
    for (int i = 0; i < T; i += 2) {   // pairs (even: rb=0, odd: rb=1)
        body(i,     0, 1);
        body(i + 1, 1, 0);
    }
    body(T, 0, 1);                     // i = 512 (flush L2 step 511)

    // ---- output head: out[b0+n] = b_out + W_out . h1(T-1) ----
    if (tid < BT) {
        float acc = b_out[0];
        #pragma unroll
        for (int u = 0; u < H; ++u) acc = fmaf(W_out[u], h1f[tid][u], acc);
        out[b0 + tid] = acc;
    }
}

extern "C" void kernel_launch(void* const* d_in, const int* in_sizes, int n_in,
                              void* d_out, int out_size, void* d_ws, size_t ws_size,
                              hipStream_t stream) {
    const float* x     = (const float*)d_in[0];
    const float* W_ih0 = (const float*)d_in[1];
    const float* W_hh0 = (const float*)d_in[2];
    const float* b_ih0 = (const float*)d_in[3];
    const float* b_hh0 = (const float*)d_in[4];
    const float* W_ih1 = (const float*)d_in[5];
    const float* W_hh1 = (const float*)d_in[6];
    const float* b_ih1 = (const float*)d_in[7];
    const float* b_hh1 = (const float*)d_in[8];
    const float* W_out = (const float*)d_in[9];
    const float* b_out = (const float*)d_in[10];
    float* out = (float*)d_out;

    const int B = out_size;          // 4096
    lstm_bf16p<<<B / BT, BLK, 0, stream>>>(x, W_ih0, W_hh0, b_ih0, b_hh0,
                                           W_ih1, W_hh1, b_ih1, b_hh1,
                                           W_out, b_out, out);
}

// Round 9
// 279.875 us; speedup vs baseline: 1.5340x; 1.1054x over previous
//
#include <hip/hip_runtime.h>
#include <cmath>

// x [B=4096][T=512][D=4], H=32, gates 4H=128 (PyTorch order i,f,g,o).
constexpr int T   = 512;
constexpr int D   = 4;
constexpr int H   = 32;
constexpr int BT  = 16;    // batch cols per block — ALL real
constexpr int BLK = 256;   // 4 waves: (layer, unit-half)

constexpr float LOG2E     = 1.44269504088896340736f;
constexpr float NEG2LOG2E = -2.88539008177792681472f;

// x staged as FULL zero-padded B-fragments (8 shorts/t). Col stride 4104
// shorts = 2052 dwords ≡ 4 (mod 32): the 16 per-iter broadcast b128 reads
// land 2-way per bank-quad (free). 16*4104*2B = 131.3 KB.
constexpr int XSTRIDE = 4104;
// h row stride 40 shorts = 20 dwords: b128 frag reads have bank-quad index
// (5*nl+q) mod 8 — exactly 2-way (nl vs nl+8) = free.
constexpr int HSTR = 40;

typedef short bf8 __attribute__((ext_vector_type(8)));  // 8 bf16 (4 VGPRs)
typedef float f4  __attribute__((ext_vector_type(4)));  // MFMA C/D
typedef float f2  __attribute__((ext_vector_type(2)));  // packed-f32 pair

// fp32 -> bf16 round-to-nearest-even (staging path)
static __device__ __forceinline__ short bf16_rtn(float v) {
    unsigned u = __float_as_uint(v);
    u += 0x7FFFu + ((u >> 16) & 1u);
    return (short)(u >> 16);
}

// R21 = R16 (best passing: 221 µs dispatch; R20's two tweaks both reverted)
// + ONE change: 4-way rcp merge in the act. Per wave-step the two act sites
// previously used 4 v_rcp (2 per pair); now each site inverts all four
// denominators with ONE rcp of the 4-product plus exact multiplies
// (1/a = R*b*(c*d) etc). Trans instrs 24 -> 22, +6 muls, fp32-exact
// (realistic denominator products << fp32 max). This is also a probe of
// trans-queue marginality: flat result => act region is latency-bound and
// the R16 structure is at its serial floor (R17 proved act-splitting and
// extra waves don't move the wall; R18-R20 structural variants all worse).
__global__ __launch_bounds__(BLK, 1) void lstm_bf16p(
    const float* __restrict__ x,
    const float* __restrict__ W_ih0, const float* __restrict__ W_hh0,
    const float* __restrict__ b_ih0, const float* __restrict__ b_hh0,
    const float* __restrict__ W_ih1, const float* __restrict__ W_hh1,
    const float* __restrict__ b_ih1, const float* __restrict__ b_hh1,
    const float* __restrict__ W_out, const float* __restrict__ b_out,
    float* __restrict__ out)
{
    __shared__ __align__(16) short xbf[16 * XSTRIDE];   // 131.3 KB staged x frags
    __shared__ __align__(16) short h0b[2][16][HSTR];    // h, [buf][col][unit]
    __shared__ __align__(16) short h1b[2][16][HSTR];
    __shared__ __align__(16) float h1f[16][36];         // final h1 fp32 for the head

    const int tid   = threadIdx.x;
    const int w     = tid >> 6;
    const int lane  = tid & 63;
    const int q     = lane >> 4;       // quad
    const int nl    = lane & 15;       // batch col (all real)
    const int layer = w >> 1;          // 0: L1, 1: L2
    const int ug    = (w & 1) << 4;    // unit group offset 0 / 16
    const int b0    = blockIdx.x * BT;

    // ---- stage x -> zero-padded bf16 fragments ----
    for (int idx = tid; idx < 16 * T; idx += BLK) {
        const int col = idx & 15;
        const int t   = idx >> 4;
        float4 xv = *(const float4*)(x + ((size_t)(b0 + col) * T + t) * D);
        bf8 v = {0, 0, 0, 0, 0, 0, 0, 0};
        v[0] = bf16_rtn(xv.x); v[1] = bf16_rtn(xv.y);
        v[2] = bf16_rtn(xv.z); v[3] = bf16_rtn(xv.w);
        *(bf8*)&xbf[col * XSTRIDE + t * 8] = v;
    }
    // zero both h buffers
    for (int idx = tid; idx < 2 * 16 * HSTR; idx += BLK) {
        (&h0b[0][0][0])[idx] = 0;
        (&h1b[0][0][0])[idx] = 0;
    }

    // ---- weights: tile g = gate type. A-frag row = 32g + ug + nl, k = 8q+j.
    const float* W1 = layer ? W_ih1 : W_hh0;
    bf8 w1[4], w2[4];
    f4  bias[4];
    #pragma unroll
    for (int g = 0; g < 4; ++g) {
        const float sc = (g == 2) ? NEG2LOG2E : -LOG2E;
        const int row = 32 * g + ug + nl;
        #pragma unroll
        for (int j = 0; j < 8; ++j) {
            w1[g][j] = bf16_rtn(W1[row * H + 8 * q + j] * sc);
            float v2 = layer ? W_hh1[row * H + 8 * q + j]
                             : ((q == 0 && j < 4) ? W_ih0[row * D + j] : 0.0f);
            w2[g][j] = bf16_rtn(v2 * sc);
        }
        #pragma unroll
        for (int r = 0; r < 4; ++r) {
            const int gr = 32 * g + ug + 4 * q + r;
            bias[g][r] = sc * (layer ? (b_ih1[gr] + b_hh1[gr])
                                     : (b_ih0[gr] + b_hh0[gr]));
        }
    }

    // cell state, fp32, lane-local — 4 units (r = 0..3)
    f4 c4 = {0.0f, 0.0f, 0.0f, 0.0f};

    const short* xcol = &xbf[nl * XSTRIDE];

    __syncthreads();

    // ---- act for all 4 units of this lane, 4-way-merged reciprocals ----
    // acc pre-scaled: -log2e*z (i,f,o) / -2log2e*z (g): native exp2 domain.
    // c' = c/(1+ef) + (1-eg)/((1+ei)(1+eg));  h = (1-ec)/((1+eo)(1+ec)).
    // Each site: Dm[0..3]; R = rcp(Dm0*Dm1*Dm2*Dm3); 1/Dm_e recovered by
    // exact muls (t0=R*s1 = 1/(Dm0*Dm1), inv0 = t0*Dm1, ...).
    auto actquad = [&](const f4 zi, const f4 zf, const f4 zg, const f4 zo,
                       unsigned& pk0, unsigned& pk1, f4& hv) {
        f4 ei, ef, eg, eo, ec;
        #pragma unroll
        for (int e = 0; e < 4; ++e) {
            ei[e] = __builtin_amdgcn_exp2f(zi[e]);
            ef[e] = __builtin_amdgcn_exp2f(zf[e]);
            eg[e] = __builtin_amdgcn_exp2f(zg[e]);
            eo[e] = __builtin_amdgcn_exp2f(zo[e]);
        }
        f4 D1 = 1.0f + ef;
        f4 D2 = (1.0f + ei) * (1.0f + eg);
        f4 Dm = D1 * D2;
        float s0 = Dm[0] * Dm[1], s1 = Dm[2] * Dm[3];
        float R  = __builtin_amdgcn_rcpf(s0 * s1);
        float t0 = R * s1, t1 = R * s0;
        f4 inv;
        inv[0] = t0 * Dm[1]; inv[1] = t0 * Dm[0];
        inv[2] = t1 * Dm[3]; inv[3] = t1 * Dm[2];
        c4 = (c4 * D2 + (1.0f - eg) * D1) * inv;
        #pragma unroll
        for (int e = 0; e < 4; ++e)
            ec[e] = __builtin_amdgcn_exp2f(c4[e] * NEG2LOG2E);
        f4 Do = (1.0f + eo) * (1.0f + ec);
        float u0 = Do[0] * Do[1], u1 = Do[2] * Do[3];
        float Q  = __builtin_amdgcn_rcpf(u0 * u1);
        float v0 = Q * u1, v1 = Q * u0;
        f4 invo;
        invo[0] = v0 * Do[1]; invo[1] = v0 * Do[0];
        invo[2] = v1 * Do[3]; invo[3] = v1 * Do[2];
        hv = (1.0f - ec) * invo;
        // dwords = [bf16(hv1)|bf16(hv0)], [bf16(hv3)|bf16(hv2)] — RNE packs
        asm("v_cvt_pk_bf16_f32 %0, %1, %2" : "=v"(pk0) : "v"(hv[0]), "v"(hv[1]));
        asm("v_cvt_pk_bf16_f32 %0, %1, %2" : "=v"(pk1) : "v"(hv[2]), "v"(hv[3]));
    };

    // ---- one timestep; rb/wb are compile-time literals at each call site ----
    auto body = [&](const int i, const int rb, const int wb) {
        // issue all DS reads first
        bf8 b2;
        if (layer == 0) {   // x(i) fragment, pre-padded (i=T reads t=0, unused)
            b2 = *(const bf8*)&xcol[(i & (T - 1)) * 8];
        } else {            // h1(i-2)
            b2 = *(const bf8*)&h1b[rb][nl][8 * q];
        }
        bf8 b1 = *(const bf8*)&h0b[rb][nl][8 * q];              // h0(i-1)

        // ---- 8 MFMAs: 4 gate tiles x 2-chain (C starts at scaled bias) ----
        f4 acc[4];
        #pragma unroll
        for (int g = 0; g < 4; ++g) {
            f4 A = __builtin_amdgcn_mfma_f32_16x16x32_bf16(w2[g], b2, bias[g], 0, 0, 0);
            A    = __builtin_amdgcn_mfma_f32_16x16x32_bf16(w1[g], b1, A,       0, 0, 0);
            acc[g] = A;
        }

        // ---- lane-local state update: units ug+4q+r, col nl ----
        const bool act = layer ? (i >= 1) : (i < T);
        if (act) {
            unsigned pk0, pk1;
            f4 hv;
            actquad(acc[0], acc[1], acc[2], acc[3], pk0, pk1, hv);
            int2 hh; hh.x = (int)pk0; hh.y = (int)pk1;
            if (layer == 0) {
                *(int2*)&h0b[wb][nl][ug + 4 * q] = hh;
            } else {
                *(int2*)&h1b[wb][nl][ug + 4 * q] = hh;
                if (i == T) {   // h1(T-1), fp32, for the output head
                    float4 hw;
                    hw.x = hv[0]; hw.y = hv[1]; hw.z = hv[2]; hw.w = hv[3];
                    *(float4*)&h1f[nl][ug + 4 * q] = hw;
                }
            }
        }
        __syncthreads();   // buffer wb becomes rb of the next step
    };

    #pragma unroll 1
    for (int i = 0; i < T; i += 2) {   // pairs (even: rb=0, odd: rb=1)
        body(i,     0, 1);
        body(i + 1, 1, 0);
    }
    body(T, 0, 1);                     // i = 512 (flush L2 step 511)

    // ---- output head: out[b0+n] = b_out + W_out . h1(T-1) ----
    if (tid < BT) {
        float acc = b_out[0];
        #pragma unroll
        for (int u = 0; u < H; ++u) acc = fmaf(W_out[u], h1f[tid][u], acc);
        out[b0 + tid] = acc;
    }
}

extern "C" void kernel_launch(void* const* d_in, const int* in_sizes, int n_in,
                              void* d_out, int out_size, void* d_ws, size_t ws_size,
                              hipStream_t stream) {
    const float* x     = (const float*)d_in[0];
    const float* W_ih0 = (const float*)d_in[1];
    const float* W_hh0 = (const float*)d_in[2];
    const float* b_ih0 = (const float*)d_in[3];
    const float* b_hh0 = (const float*)d_in[4];
    const float* W_ih1 = (const float*)d_in[5];
    const float* W_hh1 = (const float*)d_in[6];
    const float* b_ih1 = (const float*)d_in[7];
    const float* b_hh1 = (const float*)d_in[8];
    const float* W_out = (const float*)d_in[9];
    const float* b_out = (const float*)d_in[10];
    float* out = (float*)d_out;

    const int B = out_size;          // 4096
    lstm_bf16p<<<B / BT, BLK, 0, stream>>>(x, W_ih0, W_hh0, b_ih0, b_hh0,
                                           W_ih1, W_hh1, b_ih1, b_hh1,
                                           W_out, b_out, out);
}